// Round 6
// baseline (589.281 us; speedup 1.0000x reference)
//
#include <hip/hip_runtime.h>
#include <hip/hip_bf16.h>
#include <stdint.h>
#include <stddef.h>

#define NEG 0.1f
#define NB 400

typedef __attribute__((ext_vector_type(8))) short short8;
typedef __attribute__((ext_vector_type(16))) float floatx16;

__device__ __forceinline__ unsigned f2bf(float f) {
  union { float f; unsigned u; } v; v.f = f;
  unsigned r = v.u + 0x7FFFu + ((v.u >> 16) & 1u);   // RNE
  return r >> 16;
}
__device__ __forceinline__ unsigned pk2bf(float a, float b) {   // a->low16, b->high16
  __hip_bfloat162 hh = __float22bfloat162_rn(make_float2(a, b));
  union { __hip_bfloat162 h; unsigned u; } v; v.h = hh; return v.u;
}
__device__ __forceinline__ float bits2f(unsigned u) {
  union { unsigned u; float f; } v; v.u = u; return v.f;
}

// ---------------- software grid barrier (all 400 blocks co-resident by capacity)
__device__ __forceinline__ void gridbar(unsigned* cnt, int phase) {
  __syncthreads();
  if (threadIdx.x == 0) {
    __threadfence();   // release: drain writes device-wide
    __hip_atomic_fetch_add(cnt + phase, 1u, __ATOMIC_ACQ_REL, __HIP_MEMORY_SCOPE_AGENT);
    while (__hip_atomic_load(cnt + phase, __ATOMIC_ACQUIRE, __HIP_MEMORY_SCOPE_AGENT) < NB)
      __builtin_amdgcn_s_sleep(1);
  }
  __syncthreads();
  __threadfence();     // acquire: invalidate stale cache lines
}

// ---------------- conv phase: 2 waves col-split, 32 rows x 64 f-cols per block
__device__ __forceinline__ void conv_phase(
    const float* __restrict__ zin, const float* __restrict__ bnin,
    const float* __restrict__ gamv, const float* __restrict__ betv,
    const unsigned short* __restrict__ wt, const float* __restrict__ cb,
    float* __restrict__ zout, float* __restrict__ bnout, int E, int xmode,
    unsigned short* smem, int rt, int ct, int tid) {
  const int SL = (E == 512) ? 520 : 264;     // dword-stride % 32 == 4
  unsigned short* slab = smem;               // 34 x SL
  unsigned short* Bs = smem + 34 * SL;       // 2 x 64 x 72
  const int K = 3 * E, NC = K >> 6;
  const int esh = (E == 512) ? 9 : 8;
  int lane = tid & 63, wave = tid >> 6;
  int r0 = rt * 32;
  int i32 = lane & 31;
  int koff = (lane >> 5) << 3;

  int lrow = (r0 + i32) % 100;
  bool vks0 = (lrow >= 1), vks2 = (lrow <= 98);

  if (xmode) {  // conv1: x is (L,B,E) fp32, E=512
    for (int s = wave; s < 34; s += 2) {
      int m = r0 - 1 + s; m = min(max(m, 0), 3199);
      int b = m / 100, l = m - b * 100;
      size_t base = (size_t)(l * 32 + b) * 512;
#pragma unroll
      for (int cc = 0; cc < 2; ++cc) {
        int ch = cc * 256 + lane * 4;
        float4 v = *(const float4*)(zin + base + ch);
        uint2 p; p.x = pk2bf(v.x, v.y); p.y = pk2bf(v.z, v.w);
        *(uint2*)(&slab[s * SL + ch]) = p;
      }
    }
  } else {      // convs 2-4: z (m,256) fp32 with BN applied on stage
    const float inv = 1.f / 3200.f;
    float sc[4], sh[4];
#pragma unroll
    for (int q = 0; q < 4; ++q) {
      int ch = lane * 4 + q;
      float mme = bnin[ch] * inv;
      float var = bnin[256 + ch] * inv - mme * mme;
      sc[q] = gamv[ch] * rsqrtf(var + 1e-5f);
      sh[q] = betv[ch] - mme * sc[q];
    }
    for (int s = wave; s < 34; s += 2) {
      int m = r0 - 1 + s; m = min(max(m, 0), 3199);
      float4 v = *(const float4*)(zin + (size_t)m * 256 + lane * 4);
      uint2 p;
      p.x = pk2bf(v.x * sc[0] + sh[0], v.y * sc[1] + sh[1]);
      p.y = pk2bf(v.z * sc[2] + sh[2], v.w * sc[3] + sh[3]);
      *(uint2*)(&slab[s * SL + lane * 4]) = p;
    }
  }

  floatx16 acc;
#pragma unroll
  for (int q = 0; q < 16; ++q) acc[q] = 0.f;

  int brow = tid >> 1, bhalf = (tid & 1) * 32;
  uint4 pre[4];
#pragma unroll
  for (int t = 0; t < 4; ++t)
    pre[t] = *(const uint4*)(wt + (size_t)(ct * 64 + brow) * K + bhalf + t * 8);

  for (int c = 0; c < NC; ++c) {
    unsigned short* Bc = Bs + (c & 1) * (64 * 72);
#pragma unroll
    for (int t = 0; t < 4; ++t)
      *(uint4*)(&Bc[brow * 72 + bhalf + t * 8]) = pre[t];
    __syncthreads();
    if (c + 1 < NC) {
#pragma unroll
      for (int t = 0; t < 4; ++t)
        pre[t] = *(const uint4*)(wt + (size_t)(ct * 64 + brow) * K + (c + 1) * 64 + bhalf + t * 8);
    }
    int ks = (c << 6) >> esh;
    int ebase = (c << 6) & (E - 1);
    bool v = (ks == 0) ? vks0 : ((ks == 2) ? vks2 : true);
    int srow = i32 + ks;
#pragma unroll
    for (int kk = 0; kk < 4; ++kk) {
      short8 a = {};
      if (v) a = *(const short8*)(&slab[srow * SL + ebase + kk * 16 + koff]);
      short8 b8 = *(const short8*)(&Bc[(wave * 32 + i32) * 72 + kk * 16 + koff]);
      acc = __builtin_amdgcn_mfma_f32_32x32x16_bf16(a, b8, acc, 0, 0, 0);
    }
  }

  int f = ct * 64 + wave * 32 + i32;
  float bias = cb[f];
  float s1 = 0.f, s2 = 0.f;
#pragma unroll
  for (int reg = 0; reg < 16; ++reg) {
    int rowp = (reg & 3) + 8 * (reg >> 2) + 4 * (lane >> 5);
    int m = r0 + rowp;
    float v = acc[reg] + bias;
    v = fmaxf(v, NEG * v);
    zout[(size_t)m * 256 + f] = v;
    s1 += v; s2 += v * v;
  }
  s1 += __shfl_xor(s1, 32, 64);
  s2 += __shfl_xor(s2, 32, 64);
  if (lane < 32) { atomicAdd(&bnout[f], s1); atomicAdd(&bnout[256 + f], s2); }
}

// ---------------- A/C phase: fused BN4 + coords, bf16 A/C outputs
__device__ __forceinline__ void ac_phase(
    const float* __restrict__ zin, const float* __restrict__ bnin,
    const float* __restrict__ gamv, const float* __restrict__ betv,
    const unsigned short* __restrict__ wab, const float* __restrict__ hc,
    const float* __restrict__ b1v,
    unsigned short* __restrict__ Abf, unsigned short* __restrict__ Cbf,
    unsigned short* smem, int rt, int ct, int tid) {
  unsigned short* slab = smem;               // 32 x 328
  unsigned short* Bs = smem + 32 * 328;      // 2 x 64 x 72
  int lane = tid & 63, wave = tid >> 6;
  int r0 = rt * 32;
  int i32 = lane & 31;
  int koff = (lane >> 5) << 3;
  const float inv = 1.f / 3200.f;

  {
    float sc[4], sh[4];
#pragma unroll
    for (int q = 0; q < 4; ++q) {
      int ch = lane * 4 + q;
      float mme = bnin[ch] * inv;
      float var = bnin[256 + ch] * inv - mme * mme;
      sc[q] = gamv[ch] * rsqrtf(var + 1e-5f);
      sh[q] = betv[ch] - mme * sc[q];
    }
    for (int s = wave; s < 32; s += 2) {
      int m = r0 + s;
      float4 v = *(const float4*)(zin + (size_t)m * 256 + lane * 4);
      uint2 p;
      p.x = pk2bf(v.x * sc[0] + sh[0], v.y * sc[1] + sh[1]);
      p.y = pk2bf(v.z * sc[2] + sh[2], v.w * sc[3] + sh[3]);
      *(uint2*)(&slab[s * 328 + lane * 4]) = p;
    }
    if (wave == 0) {   // coords + zero tail, cols 256..319
      int s = i32, half = (lane >> 5) * 32;
      int m = r0 + s, l = m % 100;
      float c0 = ((float)l * 0.1f - 2.0f) * 0.5f;
      float c1 = ((float)(l % 10) - 2.0f) * 0.5f;
#pragma unroll
      for (int seg = 0; seg < 4; ++seg) {
        uint4 z4; z4.x = z4.y = z4.z = z4.w = 0u;
        if (half == 0 && seg == 0) z4.x = pk2bf(c0, c1);
        *(uint4*)(&slab[s * 328 + 256 + half + seg * 8]) = z4;
      }
    }
  }

  floatx16 acc;
#pragma unroll
  for (int q = 0; q < 16; ++q) acc[q] = 0.f;

  int brow = tid >> 1, bhalf = (tid & 1) * 32;
  uint4 pre[4];
#pragma unroll
  for (int t = 0; t < 4; ++t)
    pre[t] = *(const uint4*)(wab + (size_t)(ct * 64 + brow) * 384 + bhalf + t * 8);

  for (int c = 0; c < 5; ++c) {
    unsigned short* Bc = Bs + (c & 1) * (64 * 72);
#pragma unroll
    for (int t = 0; t < 4; ++t)
      *(uint4*)(&Bc[brow * 72 + bhalf + t * 8]) = pre[t];
    __syncthreads();
    if (c + 1 < 5) {
#pragma unroll
      for (int t = 0; t < 4; ++t)
        pre[t] = *(const uint4*)(wab + (size_t)(ct * 64 + brow) * 384 + (c + 1) * 64 + bhalf + t * 8);
    }
#pragma unroll
    for (int kk = 0; kk < 4; ++kk) {
      short8 a = *(const short8*)(&slab[i32 * 328 + c * 64 + kk * 16 + koff]);
      short8 b8 = *(const short8*)(&Bc[(wave * 32 + i32) * 72 + kk * 16 + koff]);
      acc = __builtin_amdgcn_mfma_f32_32x32x16_bf16(a, b8, acc, 0, 0, 0);
    }
  }

  int n = ct * 64 + wave * 32 + i32;
#pragma unroll
  for (int reg = 0; reg < 16; ++reg) {
    int rowp = (reg & 3) + 8 * (reg >> 2) + 4 * (lane >> 5);
    int m = r0 + rowp;
    float v = acc[reg];
    if (ct < 2) {
      Abf[(size_t)m * 128 + n] = (unsigned short)f2bf(v);
    } else {
      int b = m / 100;
      int nc = n - 128;
      Cbf[(size_t)m * 128 + nc] =
          (unsigned short)f2bf(v + hc[b * 128 + nc] + b1v[nc]);
    }
  }
}

// ---------------- fused chain: prep -> conv1..4 -> ac, software grid barriers
__global__ __launch_bounds__(128, 2) void k_chain(
    const float* __restrict__ x, const float* __restrict__ h,
    const float* __restrict__ cw1, const float* __restrict__ cb1,
    const float* __restrict__ g1, const float* __restrict__ be1,
    const float* __restrict__ cw2, const float* __restrict__ cb2,
    const float* __restrict__ g2, const float* __restrict__ be2,
    const float* __restrict__ cw3, const float* __restrict__ cb3,
    const float* __restrict__ g3, const float* __restrict__ be3,
    const float* __restrict__ cw4, const float* __restrict__ cb4,
    const float* __restrict__ g4, const float* __restrict__ be4,
    const float* __restrict__ W1, const float* __restrict__ b1,
    const float* __restrict__ W2, const float* __restrict__ W3,
    const float* __restrict__ W4,
    unsigned short* __restrict__ wt1, unsigned short* __restrict__ wt2,
    unsigned short* __restrict__ wt3, unsigned short* __restrict__ wt4,
    unsigned short* __restrict__ wab, unsigned short* __restrict__ wmlp,
    float* __restrict__ hc, unsigned* __restrict__ cnt,
    float* __restrict__ za, float* __restrict__ zb,
    float* __restrict__ bn0, float* __restrict__ bn1,
    float* __restrict__ bn2, float* __restrict__ bn3,
    unsigned short* __restrict__ Abf, unsigned short* __restrict__ Cbf) {
  __shared__ unsigned short smem[34 * 520 + 2 * 64 * 72];   // 53792 B
  int tid = threadIdx.x, bx = blockIdx.x;
  int gtid = bx * 128 + tid;

  // ===== phase 0: prep =====
  for (int i = gtid; i < 327680; i += 51200) {   // conv weights -> bf16 Wt[f][ks*E+e]
    const float* cw; unsigned short* wt; int E, esh, idx;
    if (i < 131072) { cw = cw1; wt = wt1; E = 512; esh = 9; idx = i; }
    else {
      int j = i - 131072; int q = j >> 16; idx = j & 65535; E = 256; esh = 8;
      cw = (q == 0) ? cw2 : ((q == 1) ? cw3 : cw4);
      wt = (q == 0) ? wt2 : ((q == 1) ? wt3 : wt4);
    }
    int f = idx >> esh, e = idx & (E - 1);
    const float* s = cw + (size_t)idx * 3;
    unsigned short* d = wt + (size_t)f * 3 * E + e;
    d[0] = (unsigned short)f2bf(s[0]);
    d[E] = (unsigned short)f2bf(s[1]);
    d[2 * E] = (unsigned short)f2bf(s[2]);
  }
  if (gtid < 49152) {    // wmlp in MFMA-fragment order (reads coalesced over n)
    int n = gtid & 127, k = (gtid >> 7) & 127, zz = gtid >> 14;
    const float* W = (zz == 0) ? W2 : ((zz == 1) ? W3 : W4);
    float v = W[k * 128 + n];
    int w = n >> 5, l = ((k >> 3) & 1) * 32 + (n & 31), kk = k >> 4, j = k & 7;
    int i = (((zz * 4 + w) * 8 + kk) << 9) | (l << 3) | j;
    wmlp[i] = (unsigned short)f2bf(v);
  }
  if (bx >= 24 && bx < 280) {   // hc partial sums: (b,seg of 64 k), 8 indep chains
    int t = bx - 24;
    int b = t >> 3, seg = t & 7;
    int k0 = seg * 64;
    const float* hr = h + b * 512 + k0;
    const float* Wc = W1 + (size_t)(516 + k0) * 128 + tid;
    float a0 = 0.f, a1 = 0.f, a2 = 0.f, a3 = 0.f, a4 = 0.f, a5 = 0.f, a6 = 0.f, a7 = 0.f;
#pragma unroll
    for (int k = 0; k < 64; k += 8) {
      a0 += hr[k + 0] * Wc[(size_t)(k + 0) * 128];
      a1 += hr[k + 1] * Wc[(size_t)(k + 1) * 128];
      a2 += hr[k + 2] * Wc[(size_t)(k + 2) * 128];
      a3 += hr[k + 3] * Wc[(size_t)(k + 3) * 128];
      a4 += hr[k + 4] * Wc[(size_t)(k + 4) * 128];
      a5 += hr[k + 5] * Wc[(size_t)(k + 5) * 128];
      a6 += hr[k + 6] * Wc[(size_t)(k + 6) * 128];
      a7 += hr[k + 7] * Wc[(size_t)(k + 7) * 128];
    }
    float s = ((a0 + a1) + (a2 + a3)) + ((a4 + a5) + (a6 + a7));
    atomicAdd(&hc[b * 128 + tid], s);
  }
  if (bx < 24) {    // wab via LDS transpose: wab[n][kp] = W1[d][n&127], kp pad->384
    float* tile = (float*)smem;   // 64 x 65 floats = 16640 B
    int half = bx / 12, rem = bx % 12, dt = rem >> 1, nt = rem & 1;
    int c = tid & 63, rq = tid >> 6;
#pragma unroll
    for (int it = 0; it < 32; ++it) {
      int r = rq + it * 2;
      int kp = dt * 64 + r;
      float v = 0.f;
      if (kp < 258) v = W1[(size_t)(half * 258 + kp) * 128 + nt * 64 + c];
      tile[r * 65 + c] = v;
    }
    __syncthreads();
#pragma unroll
    for (int it = 0; it < 32; ++it) {
      int r2 = rq + it * 2;
      wab[(size_t)(half * 128 + nt * 64 + r2) * 384 + dt * 64 + c] =
          (unsigned short)f2bf(tile[c * 65 + r2]);
    }
  }
  gridbar(cnt, 0);

  int rt = bx % 100, ct = bx / 100;
  // ===== conv chain =====
  conv_phase(x, 0, 0, 0, wt1, cb1, za, bn0, 512, 1, smem, rt, ct, tid);
  gridbar(cnt, 1);
  conv_phase(za, bn0, g1, be1, wt2, cb2, zb, bn1, 256, 0, smem, rt, ct, tid);
  gridbar(cnt, 2);
  conv_phase(zb, bn1, g2, be2, wt3, cb3, za, bn2, 256, 0, smem, rt, ct, tid);
  gridbar(cnt, 3);
  conv_phase(za, bn2, g3, be3, wt4, cb4, zb, bn3, 256, 0, smem, rt, ct, tid);
  gridbar(cnt, 4);
  // ===== A/C =====
  ac_phase(zb, bn3, g4, be4, wab, hc, b1, Abf, Cbf, smem, rt, ct, tid);
}

// ---------------- fused relation MLP: of-split waves, flipped layers 0-1,
// XOR-swizzled gs (16B chunk c -> c ^ (row&15)) -> bank-conflict-free
__global__ __launch_bounds__(256, 2) void k_mlp(
    const unsigned short* __restrict__ Abf, const unsigned short* __restrict__ Cbf,
    const unsigned short* __restrict__ wmlp, const float* __restrict__ b2,
    const float* __restrict__ b3, const float* __restrict__ b4,
    float* __restrict__ sout) {
  __shared__ unsigned short gs0[128 * 128];
  __shared__ unsigned short gs1[128 * 128];
  int tid = threadIdx.x, lane = tid & 63, wave = tid >> 6;
  int ln31 = lane & 31;
  int half = lane >> 5;
  int rx = ln31 & 15;                 // (rg*32+ln31)&15 == ln31&15

  short8 wreg[3][8];
#pragma unroll
  for (int z = 0; z < 3; ++z)
#pragma unroll
    for (int kk = 0; kk < 8; ++kk)
      wreg[z][kk] = *(const short8*)(wmlp + (size_t)(((z * 4 + wave) * 8 + kk) * 512) + lane * 8);

  int wb = wave * 32;
  float4 bq[2][4];
#pragma unroll
  for (int q = 0; q < 4; ++q) {
    bq[0][q] = *(const float4*)(b2 + wb + q * 8 + 4 * half);
    bq[1][q] = *(const float4*)(b3 + wb + q * 8 + 4 * half);
  }
  float bv4 = b4[wb + ln31];

  for (int ti = 0; ti < 2; ++ti) {
    int t = blockIdx.x + ti * 1264;
    int b = t / 79, tt = t - b * 79;
    __syncthreads();
    {  // g0 = lrelu(C_i + A_j) -> gs0 (swizzled)
      int lr = wb + (lane >> 1);
      int hh = lane & 1;
      int lbase = lr * 128, lrx = lr & 15;
      int r = tt * 128 + lr;
      if (r > 9999) r = 9999;
      const unsigned short* Crow = Cbf + (size_t)(b * 100 + r / 100) * 128;
      const unsigned short* Arow = Abf + (size_t)(b * 100 + r % 100) * 128;
#pragma unroll
      for (int it = 0; it < 8; ++it) {
        int cc = hh * 64 + it * 8;
        uint4 c4 = *(const uint4*)(Crow + cc);
        uint4 a4 = *(const uint4*)(Arow + cc);
        unsigned cw[4] = {c4.x, c4.y, c4.z, c4.w};
        unsigned aw[4] = {a4.x, a4.y, a4.z, a4.w};
        unsigned ow[4];
#pragma unroll
        for (int q = 0; q < 4; ++q) {
          float x0 = bits2f(cw[q] << 16) + bits2f(aw[q] << 16);
          float x1 = bits2f(cw[q] & 0xFFFF0000u) + bits2f(aw[q] & 0xFFFF0000u);
          x0 = fmaxf(x0, NEG * x0);
          x1 = fmaxf(x1, NEG * x1);
          ow[q] = pk2bf(x0, x1);
        }
        uint4 o4; o4.x = ow[0]; o4.y = ow[1]; o4.z = ow[2]; o4.w = ow[3];
        *(uint4*)(&gs0[lbase + (((hh * 8 + it) ^ lrx) << 3)]) = o4;
      }
    }
    __syncthreads();

    // ---- layers 0,1 flipped: D[of][pr] = sum_k W[of][k] g[pr][k]
#pragma unroll
    for (int z = 0; z < 2; ++z) {
      const unsigned short* src = z ? gs1 : gs0;
      unsigned short* dst = z ? gs0 : gs1;
#pragma unroll
      for (int rg = 0; rg < 4; ++rg) {
        floatx16 acc;
#pragma unroll
        for (int q = 0; q < 16; ++q) acc[q] = 0.f;
        int rowb = (rg * 32 + ln31) * 128;
#pragma unroll
        for (int kk = 0; kk < 8; ++kk) {
          short8 g8 = *(const short8*)(&src[rowb + (((kk * 2 + half) ^ rx) << 3)]);
          acc = __builtin_amdgcn_mfma_f32_32x32x16_bf16(wreg[z][kk], g8, acc, 0, 0, 0);
        }
        int pr = rg * 32 + ln31;
        int prb = pr * 128;
#pragma unroll
        for (int q = 0; q < 4; ++q) {
          float4 bb = bq[z][q];
          float v0 = acc[q * 4 + 0] + bb.x; v0 = fmaxf(v0, NEG * v0);
          float v1 = acc[q * 4 + 1] + bb.y; v1 = fmaxf(v1, NEG * v1);
          float v2 = acc[q * 4 + 2] + bb.z; v2 = fmaxf(v2, NEG * v2);
          float v3 = acc[q * 4 + 3] + bb.w; v3 = fmaxf(v3, NEG * v3);
          uint2 p; p.x = pk2bf(v0, v1); p.y = pk2bf(v2, v3);
          *(uint2*)(&dst[prb + (((wave * 4 + q) ^ rx) << 3) + half * 4]) = p;
        }
      }
      __syncthreads();
    }

    // ---- layer 2 unflipped: D[pr][of], reduce over pr in-register
    float colsum = 0.f;
#pragma unroll
    for (int rg = 0; rg < 4; ++rg) {
      floatx16 acc;
#pragma unroll
      for (int q = 0; q < 16; ++q) acc[q] = 0.f;
      int rowb = (rg * 32 + ln31) * 128;
#pragma unroll
      for (int kk = 0; kk < 8; ++kk) {
        short8 a8 = *(const short8*)(&gs0[rowb + (((kk * 2 + half) ^ rx) << 3)]);
        acc = __builtin_amdgcn_mfma_f32_32x32x16_bf16(a8, wreg[2][kk], acc, 0, 0, 0);
      }
#pragma unroll
      for (int reg = 0; reg < 16; ++reg) {
        int rowp = (reg & 3) + 8 * (reg >> 2) + 4 * half;
        int p = tt * 128 + rg * 32 + rowp;
        float v = acc[reg] + bv4;
        v = fmaxf(v, NEG * v);
        colsum += (p < 10000) ? v : 0.f;
      }
    }
    colsum += __shfl_xor(colsum, 32, 64);
    if (lane < 32) atomicAdd(&sout[b * 128 + wb + lane], colsum);
  }
}

// ---------------- final: out = lrelu(lrelu(s@F1+fb1)@F2+fb2), one block per b
__global__ void k_final(const float* __restrict__ s, const float* __restrict__ F1,
                        const float* __restrict__ fb1, const float* __restrict__ F2,
                        const float* __restrict__ fb2, float* __restrict__ out) {
  __shared__ float sl[128], t1[128];
  int b = blockIdx.x, t = threadIdx.x;
  if (t < 128) sl[t] = s[b * 128 + t];
  __syncthreads();
  if (t < 128) {
    float a = fb1[t];
    for (int k = 0; k < 128; ++k) a += sl[k] * F1[k * 128 + t];
    t1[t] = fmaxf(a, NEG * a);
  }
  __syncthreads();
  for (int o = t; o < 512; o += 256) {
    float a = fb2[o];
    for (int k = 0; k < 128; ++k) a += t1[k] * F2[k * 512 + o];
    out[b * 512 + o] = fmaxf(a, NEG * a);
  }
}

extern "C" void kernel_launch(void* const* d_in, const int* in_sizes, int n_in,
                              void* d_out, int out_size, void* d_ws, size_t ws_size,
                              hipStream_t stream) {
  const float* x   = (const float*)d_in[0];
  const float* h   = (const float*)d_in[1];
  const float* cw1 = (const float*)d_in[2];
  const float* cb1 = (const float*)d_in[3];
  const float* g1  = (const float*)d_in[4];
  const float* be1 = (const float*)d_in[5];
  const float* cw2 = (const float*)d_in[6];
  const float* cb2 = (const float*)d_in[7];
  const float* g2  = (const float*)d_in[8];
  const float* be2 = (const float*)d_in[9];
  const float* cw3 = (const float*)d_in[10];
  const float* cb3 = (const float*)d_in[11];
  const float* g3  = (const float*)d_in[12];
  const float* be3 = (const float*)d_in[13];
  const float* cw4 = (const float*)d_in[14];
  const float* cb4 = (const float*)d_in[15];
  const float* g4  = (const float*)d_in[16];
  const float* be4 = (const float*)d_in[17];
  const float* W1  = (const float*)d_in[18];
  const float* b1  = (const float*)d_in[19];
  const float* W2  = (const float*)d_in[20];
  const float* b2  = (const float*)d_in[21];
  const float* W3  = (const float*)d_in[22];
  const float* b3  = (const float*)d_in[23];
  const float* W4  = (const float*)d_in[24];
  const float* b4  = (const float*)d_in[25];
  const float* F1  = (const float*)d_in[26];
  const float* fb1 = (const float*)d_in[27];
  const float* F2  = (const float*)d_in[28];
  const float* fb2 = (const float*)d_in[29];

  char* ws = (char*)d_ws;
  float* bn0  = (float*)(ws + 0);
  float* bn1  = (float*)(ws + 2048);
  float* bn2  = (float*)(ws + 4096);
  float* bn3  = (float*)(ws + 6144);
  float* sbuf = (float*)(ws + 8192);                        // 32x128 fp32
  float* hc   = (float*)(ws + 24576);                       // 32x128 fp32
  unsigned* cnt = (unsigned*)(ws + 40960);                  // 8 barrier counters
  float* za   = (float*)(ws + 49152);                       // 3200x256 fp32
  float* zb   = (float*)(ws + 3325952);                     // 3200x256 fp32
  unsigned short* wt1  = (unsigned short*)(ws + 6602752);   // 256x1536 bf16
  unsigned short* wt2  = (unsigned short*)(ws + 7389184);   // 256x768
  unsigned short* wt3  = (unsigned short*)(ws + 7782400);
  unsigned short* wt4  = (unsigned short*)(ws + 8175616);
  unsigned short* wab  = (unsigned short*)(ws + 8568832);   // 256x384
  unsigned short* wmlp = (unsigned short*)(ws + 8765440);   // 3x16384 frag-order
  unsigned short* Abf  = (unsigned short*)(ws + 8863744);   // 3200x128 bf16
  unsigned short* Cbf  = (unsigned short*)(ws + 9682944);   // 3200x128 bf16; end ~10.5MB

  hipMemsetAsync(d_ws, 0, 41024, stream);    // bn sums + sbuf + hc + barrier counters

  k_chain<<<NB, 128, 0, stream>>>(
      x, h, cw1, cb1, g1, be1, cw2, cb2, g2, be2, cw3, cb3, g3, be3,
      cw4, cb4, g4, be4, W1, b1, W2, W3, W4,
      wt1, wt2, wt3, wt4, wab, wmlp, hc, cnt,
      za, zb, bn0, bn1, bn2, bn3, Abf, Cbf);

  k_mlp<<<1264, 256, 0, stream>>>(Abf, Cbf, wmlp, b2, b3, b4, sbuf);
  k_final<<<32, 256, 0, stream>>>(sbuf, F1, fb1, F2, fb2, (float*)d_out);
}

// Round 7
// 283.565 us; speedup vs baseline: 2.0781x; 2.0781x over previous
//
#include <hip/hip_runtime.h>
#include <hip/hip_bf16.h>
#include <stdint.h>
#include <stddef.h>

#define NEG 0.1f

typedef __attribute__((ext_vector_type(8))) short short8;
typedef __attribute__((ext_vector_type(16))) float floatx16;

__device__ __forceinline__ unsigned f2bf(float f) {
  union { float f; unsigned u; } v; v.f = f;
  unsigned r = v.u + 0x7FFFu + ((v.u >> 16) & 1u);   // RNE
  return r >> 16;
}
__device__ __forceinline__ unsigned pk2bf(float a, float b) {   // a->low16, b->high16
  __hip_bfloat162 hh = __float22bfloat162_rn(make_float2(a, b));
  union { __hip_bfloat162 h; unsigned u; } v; v.h = hh; return v.u;
}
__device__ __forceinline__ float bits2f(unsigned u) {
  union { unsigned u; float f; } v; v.u = u; return v.f;
}

// ---------------- fused prep: conv-w bf16 | wab (LDS transpose) | wmlp | hc (k-split)
__global__ void k_prep(const float* __restrict__ cw1, const float* __restrict__ cw2,
                       const float* __restrict__ cw3, const float* __restrict__ cw4,
                       unsigned short* __restrict__ wt1, unsigned short* __restrict__ wt2,
                       unsigned short* __restrict__ wt3, unsigned short* __restrict__ wt4,
                       const float* __restrict__ W1, unsigned short* __restrict__ wab,
                       const float* __restrict__ W2, const float* __restrict__ W3,
                       const float* __restrict__ W4, unsigned short* __restrict__ wmlp,
                       const float* __restrict__ h, float* __restrict__ hc) {
  __shared__ float tile[64 * 65];
  int bid = blockIdx.x, tid = threadIdx.x;
  if (bid < 1280) {                       // conv weights: Wt[f][ks*E+e] = cw[f][e][ks]
    int z = bid;
    int E; const float* cw; unsigned short* wt;
    if (z < 512) { E = 512; cw = cw1; wt = wt1; }
    else {
      int q = (z - 512) >> 8; E = 256;
      cw = (q == 0) ? cw2 : ((q == 1) ? cw3 : cw4);
      wt = (q == 0) ? wt2 : ((q == 1) ? wt3 : wt4);
      z = (z - 512) & 255;
    }
    int idx = z * 256 + tid;              // over F*E
    int f = idx / E, e = idx - f * E;
    const float* s = cw + (size_t)idx * 3;
    unsigned short* d = wt + (size_t)f * 3 * E + e;
    d[0] = (unsigned short)f2bf(s[0]);
    d[E] = (unsigned short)f2bf(s[1]);
    d[2 * E] = (unsigned short)f2bf(s[2]);
  } else if (bid < 1304) {                // wab via LDS transpose: wab[n][kp]=W1[d][n&127]
    int tw = bid - 1280;                  // 24 tiles: half(2) x dt(6) x nt(2)
    int half = tw / 12, rem = tw % 12, dt = rem >> 1, nt = rem & 1;
    int c = tid & 63, rq = tid >> 6;
#pragma unroll
    for (int it = 0; it < 16; ++it) {
      int r = rq + it * 4;
      int kp = dt * 64 + r;
      float v = 0.f;
      if (kp < 258) v = W1[(size_t)(half * 258 + kp) * 128 + nt * 64 + c];
      tile[r * 65 + c] = v;
    }
    __syncthreads();
#pragma unroll
    for (int it = 0; it < 16; ++it) {
      int r2 = rq + it * 4;
      wab[(size_t)(half * 128 + nt * 64 + r2) * 384 + dt * 64 + c] =
          (unsigned short)f2bf(tile[c * 65 + r2]);
    }
  } else if (bid < 1496) {                // wmlp frag-order, reads coalesced over n
    int i2 = (bid - 1304) * 256 + tid;    // z(3) x k(128) x n(128)
    int n = i2 & 127, k = (i2 >> 7) & 127, zz = i2 >> 14;
    const float* W = (zz == 0) ? W2 : ((zz == 1) ? W3 : W4);
    float v = W[k * 128 + n];
    int w = n >> 5, l = ((k >> 3) & 1) * 32 + (n & 31), kk = k >> 4, j = k & 7;
    int i = (((zz * 4 + w) * 8 + kk) << 9) | (l << 3) | j;
    wmlp[i] = (unsigned short)f2bf(v);
  } else {                                // hc partial: 128 blocks = b(32) x seg(4)
    int t = bid - 1496;
    int b = t >> 2, seg = t & 3;
    int m = tid & 127, sub = tid >> 7;
    int k0 = seg * 128 + sub * 64;
    const float* hr = h + b * 512 + k0;
    const float* Wc = W1 + (size_t)(516 + k0) * 128 + m;
    float a0 = 0.f, a1 = 0.f, a2 = 0.f, a3 = 0.f, a4 = 0.f, a5 = 0.f, a6 = 0.f, a7 = 0.f;
#pragma unroll
    for (int k = 0; k < 64; k += 8) {
      a0 += hr[k + 0] * Wc[(size_t)(k + 0) * 128];
      a1 += hr[k + 1] * Wc[(size_t)(k + 1) * 128];
      a2 += hr[k + 2] * Wc[(size_t)(k + 2) * 128];
      a3 += hr[k + 3] * Wc[(size_t)(k + 3) * 128];
      a4 += hr[k + 4] * Wc[(size_t)(k + 4) * 128];
      a5 += hr[k + 5] * Wc[(size_t)(k + 5) * 128];
      a6 += hr[k + 6] * Wc[(size_t)(k + 6) * 128];
      a7 += hr[k + 7] * Wc[(size_t)(k + 7) * 128];
    }
    float s = ((a0 + a1) + (a2 + a3)) + ((a4 + a5) + (a6 + a7));
    atomicAdd(&hc[b * 128 + m], s);
  }
}

// ---------------- conv: 256 thr = 4 waves; K-split x2 across wave pairs,
// col-split x2 within pair. Tile 32 rows x 64 f-cols. LDS scratch combine.
__global__ __launch_bounds__(256, 2) void k_conv(
    const float* __restrict__ zin, const float* __restrict__ bnin,
    const float* __restrict__ gamv, const float* __restrict__ betv,
    const unsigned short* __restrict__ wt, const float* __restrict__ cb,
    float* __restrict__ zout, float* __restrict__ bnout, int E, int xmode) {
  extern __shared__ unsigned short smem[];
  const int SL = (E == 512) ? 520 : 264;     // dword-stride % 32 == 4
  unsigned short* slab = smem;               // 34 x SL
  unsigned short* Bs = smem + 34 * SL;       // 2(khalf) x 2(dbuf) x 64 x 72
  const int K = 3 * E, NC = K >> 6, NCH = NC >> 1;
  const int esh = (E == 512) ? 9 : 8;
  int tid = threadIdx.x;
  int lane = tid & 63, wave = tid >> 6;
  int khalf = wave >> 1, cwave = wave & 1;
  int r0 = blockIdx.x * 32, ct = blockIdx.y;
  int i32 = lane & 31;
  int koff = (lane >> 5) << 3;

  int lrow = (r0 + i32) % 100;
  bool vks0 = (lrow >= 1), vks2 = (lrow <= 98);

  // ---- stage input slab, 4 waves
  if (xmode) {  // conv1: x is (L,B,E) fp32, E=512
    for (int s = wave; s < 34; s += 4) {
      int m = r0 - 1 + s; m = min(max(m, 0), 3199);
      int b = m / 100, l = m - b * 100;
      size_t base = (size_t)(l * 32 + b) * 512;
#pragma unroll
      for (int cc = 0; cc < 2; ++cc) {
        int ch = cc * 256 + lane * 4;
        float4 v = *(const float4*)(zin + base + ch);
        uint2 p; p.x = pk2bf(v.x, v.y); p.y = pk2bf(v.z, v.w);
        *(uint2*)(&slab[s * SL + ch]) = p;
      }
    }
  } else {      // convs 2-4: z (m,256) fp32 with BN applied on stage
    const float inv = 1.f / 3200.f;
    float sc[4], sh[4];
#pragma unroll
    for (int q = 0; q < 4; ++q) {
      int ch = lane * 4 + q;
      float mme = bnin[ch] * inv;
      float var = bnin[256 + ch] * inv - mme * mme;
      sc[q] = gamv[ch] * rsqrtf(var + 1e-5f);
      sh[q] = betv[ch] - mme * sc[q];
    }
    for (int s = wave; s < 34; s += 4) {
      int m = r0 - 1 + s; m = min(max(m, 0), 3199);
      float4 v = *(const float4*)(zin + (size_t)m * 256 + lane * 4);
      uint2 p;
      p.x = pk2bf(v.x * sc[0] + sh[0], v.y * sc[1] + sh[1]);
      p.y = pk2bf(v.z * sc[2] + sh[2], v.w * sc[3] + sh[3]);
      *(uint2*)(&slab[s * SL + lane * 4]) = p;
    }
  }

  floatx16 acc;
#pragma unroll
  for (int q = 0; q < 16; ++q) acc[q] = 0.f;

  // B staging: each K-half's 128 threads stage their own chunks
  int t128 = tid & 127;
  int brow = t128 >> 1, bhalf = (t128 & 1) * 32;
  const unsigned short* wrow = wt + (size_t)(ct * 64 + brow) * K + khalf * NCH * 64 + bhalf;
  uint4 pre[4];
#pragma unroll
  for (int t = 0; t < 4; ++t) pre[t] = *(const uint4*)(wrow + t * 8);

  for (int c = 0; c < NCH; ++c) {
    unsigned short* Bc = Bs + (khalf * 2 + (c & 1)) * (64 * 72);
#pragma unroll
    for (int t = 0; t < 4; ++t)
      *(uint4*)(&Bc[brow * 72 + bhalf + t * 8]) = pre[t];
    __syncthreads();      // covers slab staging at c==0
    if (c + 1 < NCH) {
#pragma unroll
      for (int t = 0; t < 4; ++t)
        pre[t] = *(const uint4*)(wrow + (c + 1) * 64 + t * 8);
    }
    int cg = khalf * NCH + c;
    int ks = (cg << 6) >> esh;
    int ebase = (cg << 6) & (E - 1);
    bool v = (ks == 0) ? vks0 : ((ks == 2) ? vks2 : true);
    int srow = i32 + ks;
#pragma unroll
    for (int kk = 0; kk < 4; ++kk) {
      short8 a = {};
      if (v) a = *(const short8*)(&slab[srow * SL + ebase + kk * 16 + koff]);
      short8 b8 = *(const short8*)(&Bc[(cwave * 32 + i32) * 72 + kk * 16 + koff]);
      acc = __builtin_amdgcn_mfma_f32_32x32x16_bf16(a, b8, acc, 0, 0, 0);
    }
  }

  // ---- combine K-halves via LDS scratch (reuses slab region)
  __syncthreads();
  float* scr = (float*)smem;           // 2 x 32 x 32 floats = 8 KB
  if (khalf == 1) {
#pragma unroll
    for (int reg = 0; reg < 16; ++reg) {
      int rowp = (reg & 3) + 8 * (reg >> 2) + 4 * (lane >> 5);
      scr[cwave * 1024 + rowp * 32 + i32] = acc[reg];
    }
  }
  __syncthreads();
  if (khalf == 0) {
    int f = ct * 64 + cwave * 32 + i32;
    float bias = cb[f];
    float s1 = 0.f, s2 = 0.f;
#pragma unroll
    for (int reg = 0; reg < 16; ++reg) {
      int rowp = (reg & 3) + 8 * (reg >> 2) + 4 * (lane >> 5);
      int m = r0 + rowp;
      float v = acc[reg] + scr[cwave * 1024 + rowp * 32 + i32] + bias;
      v = fmaxf(v, NEG * v);
      zout[(size_t)m * 256 + f] = v;
      s1 += v; s2 += v * v;
    }
    s1 += __shfl_xor(s1, 32, 64);
    s2 += __shfl_xor(s2, 32, 64);
    if (lane < 32) { atomicAdd(&bnout[f], s1); atomicAdd(&bnout[256 + f], s2); }
  }
}

// ---------------- A/C GEMM, 128 thr = 2 waves col-split, fused BN4 + coords
__global__ __launch_bounds__(128, 2) void k_ac(
    const float* __restrict__ zin, const float* __restrict__ bnin,
    const float* __restrict__ gamv, const float* __restrict__ betv,
    const unsigned short* __restrict__ wab, const float* __restrict__ hc,
    const float* __restrict__ b1v,
    unsigned short* __restrict__ Abf, unsigned short* __restrict__ Cbf) {
  __shared__ unsigned short slab[32 * 328];
  __shared__ unsigned short Bs[2 * 64 * 72];
  int tid = threadIdx.x;
  int lane = tid & 63, wave = tid >> 6;
  int r0 = blockIdx.x * 32, ct = blockIdx.y;
  int i32 = lane & 31;
  int koff = (lane >> 5) << 3;
  const float inv = 1.f / 3200.f;

  {
    float sc[4], sh[4];
#pragma unroll
    for (int q = 0; q < 4; ++q) {
      int ch = lane * 4 + q;
      float mme = bnin[ch] * inv;
      float var = bnin[256 + ch] * inv - mme * mme;
      sc[q] = gamv[ch] * rsqrtf(var + 1e-5f);
      sh[q] = betv[ch] - mme * sc[q];
    }
    for (int s = wave; s < 32; s += 2) {
      int m = r0 + s;
      float4 v = *(const float4*)(zin + (size_t)m * 256 + lane * 4);
      uint2 p;
      p.x = pk2bf(v.x * sc[0] + sh[0], v.y * sc[1] + sh[1]);
      p.y = pk2bf(v.z * sc[2] + sh[2], v.w * sc[3] + sh[3]);
      *(uint2*)(&slab[s * 328 + lane * 4]) = p;
    }
    if (wave == 0) {   // coords + zero tail, cols 256..319
      int s = i32, half = (lane >> 5) * 32;
      int m = r0 + s, l = m % 100;
      float c0 = ((float)l * 0.1f - 2.0f) * 0.5f;
      float c1 = ((float)(l % 10) - 2.0f) * 0.5f;
#pragma unroll
      for (int seg = 0; seg < 4; ++seg) {
        uint4 z4; z4.x = z4.y = z4.z = z4.w = 0u;
        if (half == 0 && seg == 0) z4.x = pk2bf(c0, c1);
        *(uint4*)(&slab[s * 328 + 256 + half + seg * 8]) = z4;
      }
    }
  }

  floatx16 acc;
#pragma unroll
  for (int q = 0; q < 16; ++q) acc[q] = 0.f;

  int brow = tid >> 1, bhalf = (tid & 1) * 32;
  uint4 pre[4];
#pragma unroll
  for (int t = 0; t < 4; ++t)
    pre[t] = *(const uint4*)(wab + (size_t)(ct * 64 + brow) * 384 + bhalf + t * 8);

  for (int c = 0; c < 5; ++c) {
    unsigned short* Bc = Bs + (c & 1) * (64 * 72);
#pragma unroll
    for (int t = 0; t < 4; ++t)
      *(uint4*)(&Bc[brow * 72 + bhalf + t * 8]) = pre[t];
    __syncthreads();
    if (c + 1 < 5) {
#pragma unroll
      for (int t = 0; t < 4; ++t)
        pre[t] = *(const uint4*)(wab + (size_t)(ct * 64 + brow) * 384 + (c + 1) * 64 + bhalf + t * 8);
    }
#pragma unroll
    for (int kk = 0; kk < 4; ++kk) {
      short8 a = *(const short8*)(&slab[i32 * 328 + c * 64 + kk * 16 + koff]);
      short8 b8 = *(const short8*)(&Bc[(wave * 32 + i32) * 72 + kk * 16 + koff]);
      acc = __builtin_amdgcn_mfma_f32_32x32x16_bf16(a, b8, acc, 0, 0, 0);
    }
  }

  int n = ct * 64 + wave * 32 + i32;
#pragma unroll
  for (int reg = 0; reg < 16; ++reg) {
    int rowp = (reg & 3) + 8 * (reg >> 2) + 4 * (lane >> 5);
    int m = r0 + rowp;
    float v = acc[reg];
    if (ct < 2) {
      Abf[(size_t)m * 128 + n] = (unsigned short)f2bf(v);
    } else {
      int b = m / 100;
      int nc = n - 128;
      Cbf[(size_t)m * 128 + nc] =
          (unsigned short)f2bf(v + hc[b * 128 + nc] + b1v[nc]);
    }
  }
}

// ---------------- fused relation MLP: of-split waves, flipped layers 0-1,
// XOR-swizzled gs (16B chunk c -> c ^ (row&15)) -> bank-balanced
__global__ __launch_bounds__(256, 2) void k_mlp(
    const unsigned short* __restrict__ Abf, const unsigned short* __restrict__ Cbf,
    const unsigned short* __restrict__ wmlp, const float* __restrict__ b2,
    const float* __restrict__ b3, const float* __restrict__ b4,
    float* __restrict__ sout) {
  __shared__ unsigned short gs0[128 * 128];
  __shared__ unsigned short gs1[128 * 128];
  int tid = threadIdx.x, lane = tid & 63, wave = tid >> 6;
  int ln31 = lane & 31;
  int half = lane >> 5;
  int rx = ln31 & 15;                 // (rg*32+ln31)&15 == ln31&15

  short8 wreg[3][8];
#pragma unroll
  for (int z = 0; z < 3; ++z)
#pragma unroll
    for (int kk = 0; kk < 8; ++kk)
      wreg[z][kk] = *(const short8*)(wmlp + (size_t)(((z * 4 + wave) * 8 + kk) * 512) + lane * 8);

  int wb = wave * 32;
  float4 bq[2][4];
#pragma unroll
  for (int q = 0; q < 4; ++q) {
    bq[0][q] = *(const float4*)(b2 + wb + q * 8 + 4 * half);
    bq[1][q] = *(const float4*)(b3 + wb + q * 8 + 4 * half);
  }
  float bv4 = b4[wb + ln31];

  for (int ti = 0; ti < 2; ++ti) {
    int t = blockIdx.x + ti * 1264;
    int b = t / 79, tt = t - b * 79;
    __syncthreads();
    {  // g0 = lrelu(C_i + A_j) -> gs0 (swizzled)
      int lr = wb + (lane >> 1);
      int hh = lane & 1;
      int lbase = lr * 128, lrx = lr & 15;
      int r = tt * 128 + lr;
      if (r > 9999) r = 9999;
      const unsigned short* Crow = Cbf + (size_t)(b * 100 + r / 100) * 128;
      const unsigned short* Arow = Abf + (size_t)(b * 100 + r % 100) * 128;
#pragma unroll
      for (int it = 0; it < 8; ++it) {
        int cc = hh * 64 + it * 8;
        uint4 c4 = *(const uint4*)(Crow + cc);
        uint4 a4 = *(const uint4*)(Arow + cc);
        unsigned cw[4] = {c4.x, c4.y, c4.z, c4.w};
        unsigned aw[4] = {a4.x, a4.y, a4.z, a4.w};
        unsigned ow[4];
#pragma unroll
        for (int q = 0; q < 4; ++q) {
          float x0 = bits2f(cw[q] << 16) + bits2f(aw[q] << 16);
          float x1 = bits2f(cw[q] & 0xFFFF0000u) + bits2f(aw[q] & 0xFFFF0000u);
          x0 = fmaxf(x0, NEG * x0);
          x1 = fmaxf(x1, NEG * x1);
          ow[q] = pk2bf(x0, x1);
        }
        uint4 o4; o4.x = ow[0]; o4.y = ow[1]; o4.z = ow[2]; o4.w = ow[3];
        *(uint4*)(&gs0[lbase + (((hh * 8 + it) ^ lrx) << 3)]) = o4;
      }
    }
    __syncthreads();

    // ---- layers 0,1 flipped: D[of][pr] = sum_k W[of][k] g[pr][k]
#pragma unroll
    for (int z = 0; z < 2; ++z) {
      const unsigned short* src = z ? gs1 : gs0;
      unsigned short* dst = z ? gs0 : gs1;
#pragma unroll
      for (int rg = 0; rg < 4; ++rg) {
        floatx16 acc;
#pragma unroll
        for (int q = 0; q < 16; ++q) acc[q] = 0.f;
        int rowb = (rg * 32 + ln31) * 128;
#pragma unroll
        for (int kk = 0; kk < 8; ++kk) {
          short8 g8 = *(const short8*)(&src[rowb + (((kk * 2 + half) ^ rx) << 3)]);
          acc = __builtin_amdgcn_mfma_f32_32x32x16_bf16(wreg[z][kk], g8, acc, 0, 0, 0);
        }
        int pr = rg * 32 + ln31;
        int prb = pr * 128;
#pragma unroll
        for (int q = 0; q < 4; ++q) {
          float4 bb = bq[z][q];
          float v0 = acc[q * 4 + 0] + bb.x; v0 = fmaxf(v0, NEG * v0);
          float v1 = acc[q * 4 + 1] + bb.y; v1 = fmaxf(v1, NEG * v1);
          float v2 = acc[q * 4 + 2] + bb.z; v2 = fmaxf(v2, NEG * v2);
          float v3 = acc[q * 4 + 3] + bb.w; v3 = fmaxf(v3, NEG * v3);
          uint2 p; p.x = pk2bf(v0, v1); p.y = pk2bf(v2, v3);
          *(uint2*)(&dst[prb + (((wave * 4 + q) ^ rx) << 3) + half * 4]) = p;
        }
      }
      __syncthreads();
    }

    // ---- layer 2 unflipped: D[pr][of], reduce over pr in-register
    float colsum = 0.f;
#pragma unroll
    for (int rg = 0; rg < 4; ++rg) {
      floatx16 acc;
#pragma unroll
      for (int q = 0; q < 16; ++q) acc[q] = 0.f;
      int rowb = (rg * 32 + ln31) * 128;
#pragma unroll
      for (int kk = 0; kk < 8; ++kk) {
        short8 a8 = *(const short8*)(&gs0[rowb + (((kk * 2 + half) ^ rx) << 3)]);
        acc = __builtin_amdgcn_mfma_f32_32x32x16_bf16(a8, wreg[2][kk], acc, 0, 0, 0);
      }
#pragma unroll
      for (int reg = 0; reg < 16; ++reg) {
        int rowp = (reg & 3) + 8 * (reg >> 2) + 4 * half;
        int p = tt * 128 + rg * 32 + rowp;
        float v = acc[reg] + bv4;
        v = fmaxf(v, NEG * v);
        colsum += (p < 10000) ? v : 0.f;
      }
    }
    colsum += __shfl_xor(colsum, 32, 64);
    if (lane < 32) atomicAdd(&sout[b * 128 + wb + lane], colsum);
  }
}

// ---------------- final: out = lrelu(lrelu(s@F1+fb1)@F2+fb2), one block per b
__global__ void k_final(const float* __restrict__ s, const float* __restrict__ F1,
                        const float* __restrict__ fb1, const float* __restrict__ F2,
                        const float* __restrict__ fb2, float* __restrict__ out) {
  __shared__ float sl[128], t1[128];
  int b = blockIdx.x, t = threadIdx.x;
  if (t < 128) sl[t] = s[b * 128 + t];
  __syncthreads();
  if (t < 128) {
    float a = fb1[t];
    for (int k = 0; k < 128; ++k) a += sl[k] * F1[k * 128 + t];
    t1[t] = fmaxf(a, NEG * a);
  }
  __syncthreads();
  for (int o = t; o < 512; o += 256) {
    float a = fb2[o];
    for (int k = 0; k < 128; ++k) a += t1[k] * F2[k * 512 + o];
    out[b * 512 + o] = fmaxf(a, NEG * a);
  }
}

extern "C" void kernel_launch(void* const* d_in, const int* in_sizes, int n_in,
                              void* d_out, int out_size, void* d_ws, size_t ws_size,
                              hipStream_t stream) {
  const float* x   = (const float*)d_in[0];
  const float* h   = (const float*)d_in[1];
  const float* cw1 = (const float*)d_in[2];
  const float* cb1 = (const float*)d_in[3];
  const float* g1  = (const float*)d_in[4];
  const float* be1 = (const float*)d_in[5];
  const float* cw2 = (const float*)d_in[6];
  const float* cb2 = (const float*)d_in[7];
  const float* g2  = (const float*)d_in[8];
  const float* be2 = (const float*)d_in[9];
  const float* cw3 = (const float*)d_in[10];
  const float* cb3 = (const float*)d_in[11];
  const float* g3  = (const float*)d_in[12];
  const float* be3 = (const float*)d_in[13];
  const float* cw4 = (const float*)d_in[14];
  const float* cb4 = (const float*)d_in[15];
  const float* g4  = (const float*)d_in[16];
  const float* be4 = (const float*)d_in[17];
  const float* W1  = (const float*)d_in[18];
  const float* b1  = (const float*)d_in[19];
  const float* W2  = (const float*)d_in[20];
  const float* b2  = (const float*)d_in[21];
  const float* W3  = (const float*)d_in[22];
  const float* b3  = (const float*)d_in[23];
  const float* W4  = (const float*)d_in[24];
  const float* b4  = (const float*)d_in[25];
  const float* F1  = (const float*)d_in[26];
  const float* fb1 = (const float*)d_in[27];
  const float* F2  = (const float*)d_in[28];
  const float* fb2 = (const float*)d_in[29];

  char* ws = (char*)d_ws;
  float* bn0  = (float*)(ws + 0);
  float* bn1  = (float*)(ws + 2048);
  float* bn2  = (float*)(ws + 4096);
  float* bn3  = (float*)(ws + 6144);
  float* sbuf = (float*)(ws + 8192);                        // 32x128 fp32
  float* hc   = (float*)(ws + 24576);                       // 32x128 fp32 (zeroed)
  float* za   = (float*)(ws + 40960);                       // 3200x256 fp32
  float* zb   = (float*)(ws + 3317760);                     // 3200x256 fp32
  unsigned short* wt1  = (unsigned short*)(ws + 6594560);   // 256x1536 bf16
  unsigned short* wt2  = (unsigned short*)(ws + 7380992);   // 256x768
  unsigned short* wt3  = (unsigned short*)(ws + 7774208);
  unsigned short* wt4  = (unsigned short*)(ws + 8167424);
  unsigned short* wab  = (unsigned short*)(ws + 8560640);   // 256x384
  unsigned short* wmlp = (unsigned short*)(ws + 8757248);   // 3x16384 frag-order
  unsigned short* Abf  = (unsigned short*)(ws + 8855552);   // 3200x128 bf16
  unsigned short* Cbf  = (unsigned short*)(ws + 9674752);   // 3200x128 bf16; end 10493952

  hipMemsetAsync(d_ws, 0, 40960, stream);     // bn sums + sbuf + hc

  k_prep<<<1624, 256, 0, stream>>>(cw1, cw2, cw3, cw4, wt1, wt2, wt3, wt4,
                                   W1, wab, W2, W3, W4, wmlp, h, hc);

  const int lds1 = (34 * 520 + 4 * 64 * 72) * 2;   // 72224 B
  const int lds2 = (34 * 264 + 4 * 64 * 72) * 2;   // 54816 B
  k_conv<<<dim3(100, 4), 256, lds1, stream>>>(x,  nullptr, nullptr, nullptr, wt1, cb1, za, bn0, 512, 1);
  k_conv<<<dim3(100, 4), 256, lds2, stream>>>(za, bn0, g1, be1, wt2, cb2, zb, bn1, 256, 0);
  k_conv<<<dim3(100, 4), 256, lds2, stream>>>(zb, bn1, g2, be2, wt3, cb3, za, bn2, 256, 0);
  k_conv<<<dim3(100, 4), 256, lds2, stream>>>(za, bn2, g3, be3, wt4, cb4, zb, bn3, 256, 0);

  k_ac<<<dim3(100, 4), 128, 0, stream>>>(zb, bn3, g4, be4, wab, hc, b1, Abf, Cbf);

  k_mlp<<<1264, 256, 0, stream>>>(Abf, Cbf, wmlp, b2, b3, b4, sbuf);
  k_final<<<32, 256, 0, stream>>>(sbuf, F1, fb1, F2, fb2, (float*)d_out);
}